// Round 1
// baseline (9640.414 us; speedup 1.0000x reference)
//
#include <hip/hip_runtime.h>
#include <math.h>
#include <stdint.h>

#define D     512
#define DFF   2048
#define BB    8
#define NH    8
#define HD    64
#define NV    32000
#define NL    4
#define TMAX  17
#define KC    64
#define STEPS 16
#define KTOP  50
#define PAD_ID 0
#define BOS_ID 2
#define EOS_ID 3

// ---------------- threefry2x32 (matches jax lowering exactly) ----------------
__host__ __device__ inline void tf2x32(unsigned k0, unsigned k1, unsigned x0, unsigned x1,
                                       unsigned& o0, unsigned& o1)
{
  unsigned ks2 = k0 ^ k1 ^ 0x1BD11BDAu;
#define TFR(r) { x0 += x1; x1 = (x1 << (r)) | (x1 >> (32 - (r))); x1 ^= x0; }
  x0 += k0; x1 += k1;
  TFR(13) TFR(15) TFR(26) TFR(6)
  x0 += k1;  x1 += ks2 + 1u;
  TFR(17) TFR(29) TFR(16) TFR(24)
  x0 += ks2; x1 += k0 + 2u;
  TFR(13) TFR(15) TFR(26) TFR(6)
  x0 += k0;  x1 += k1 + 3u;
  TFR(17) TFR(29) TFR(16) TFR(24)
  x0 += k1;  x1 += ks2 + 4u;
  TFR(13) TFR(15) TFR(26) TFR(6)
  o0 = x0 + ks2; o1 = x1 + k0 + 5u;
#undef TFR
}

__device__ inline float wredf(float v) {
  for (int o = 32; o > 0; o >>= 1) v += __shfl_xor(v, o, 64);
  return v;
}

// ---------------- init: BOS token + finished flags ----------------
__global__ void init_k(int* toks, int* fin) {
  int i = threadIdx.x;
  if (i < BB) { toks[i * TMAX + 0] = BOS_ID; fin[i] = 0; }
}

// ---------------- cross-attention K/V precompute ----------------
// grid.x = NL*KC*256 (gx = (l<<14)|(kpos<<8)|jblk), grid.y = B, block 256
__global__ void cross_kv_k(const float* __restrict__ state, const float* __restrict__ qkvw,
                           const float* __restrict__ qkvb, float* __restrict__ cK,
                           float* __restrict__ cV)
{
  int gx = blockIdx.x;
  int b = blockIdx.y;
  int jblk = gx & 255, kpos = (gx >> 8) & 63, l = gx >> 14;
  int j = jblk * 4 + (threadIdx.x >> 6);   // 0..1023
  int lane = threadIdx.x & 63;
  const float* xr = state + ((size_t)b * KC + kpos) * D;
  int row = D + j;                          // wqkv rows 512..1535 (K then V)
  const float* wr = qkvw + (((size_t)l * 2 + 1) * (3 * D) + row) * D;
  float acc = 0.f;
  for (int e = lane; e < D; e += 64) acc += xr[e] * wr[e];
  acc = wredf(acc);
  if (lane == 0) {
    float v = acc + qkvb[((size_t)l * 2 + 1) * (3 * D) + row];
    float* dst = (j < D) ? cK : cV;
    int jj = (j < D) ? j : j - D;
    dst[(((size_t)l * BB + b) * KC + kpos) * D + jj] = v;
  }
}

// ---------------- embedding + sinusoidal positional encoding ----------------
__global__ void embed_k(const int* __restrict__ toks, const float* __restrict__ emb,
                        float* __restrict__ x, int t)
{
  int b = blockIdx.x, j = threadIdx.x;       // block 512
  int tok = toks[b * TMAX + t];
  const float SQRT_D = (float)22.627416997969522;           // np.sqrt(512) -> f32
  const float C = (float)(9.210340371976184 / 512.0);       // log(1e4)/d  -> f32
  float e = emb[(size_t)tok * D + j] * SQRT_D;
  float i2 = (float)(j & ~1);
  float omega = expf(-i2 * C);
  float val = (float)t * omega;
  float pe = (j & 1) ? cosf(val) : sinf(val);
  x[b * D + j] = e + pe;
}

// ---------------- generic wave-per-output GEMV ----------------
// out[b*nout+j] = act( dot(X[b],W[j]) + bias[j] + (RES? R[b*nout+j] : 0) )
template <int ACT, int RES>
__global__ void gemv_k(const float* __restrict__ X, const float* __restrict__ W,
                       const float* __restrict__ bias, const float* __restrict__ Rsrc,
                       float* __restrict__ out, int din, int nout)
{
  int b = blockIdx.y;
  int j = blockIdx.x * 4 + (threadIdx.x >> 6);
  int lane = threadIdx.x & 63;
  if (j >= nout) return;
  const float* xr = X + (size_t)b * din;
  const float* wr = W + (size_t)j * din;
  float acc = 0.f;
  for (int e = lane; e < din; e += 64) acc += xr[e] * wr[e];
  acc = wredf(acc);
  if (lane == 0) {
    float v = acc + bias[j];
    if (RES) v += Rsrc[(size_t)b * nout + j];
    if (ACT == 1) {
      const float SQRT2 = (float)1.4142135623730951;
      v = v * (erff(v / SQRT2) + 1.0f) / 2.0f;   // exact GELU, jax op order
    }
    out[(size_t)b * nout + j] = v;
  }
}

// ---------------- fused self-attn QKV projection (routes q/k/v) ----------------
__global__ void qkv_self_k(const float* __restrict__ X, const float* __restrict__ W,
                           const float* __restrict__ bias, float* __restrict__ qb,
                           float* __restrict__ sK, float* __restrict__ sV, int l, int t)
{
  int b = blockIdx.y;
  int j = blockIdx.x * 4 + (threadIdx.x >> 6);  // 0..1535
  int lane = threadIdx.x & 63;
  const float* xr = X + (size_t)b * D;
  const float* wr = W + (size_t)j * D;
  float acc = 0.f;
  for (int e = lane; e < D; e += 64) acc += xr[e] * wr[e];
  acc = wredf(acc);
  if (lane == 0) {
    float v = acc + bias[j];
    if (j < D)           qb[b * D + j] = v;
    else if (j < 2 * D)  sK[(((size_t)l * BB + b) * TMAX + t) * D + (j - D)] = v;
    else                 sV[(((size_t)l * BB + b) * TMAX + t) * D + (j - 2 * D)] = v;
  }
}

// ---------------- causal self-attention over cached K/V (T = t+1 keys) ----------------
__global__ void attn_self_k(const float* __restrict__ qb, const float* __restrict__ sK,
                            const float* __restrict__ sV, float* __restrict__ ao, int l, int t)
{
  int b = blockIdx.x, h = blockIdx.y, lane = threadIdx.x;   // block 64
  int T = t + 1;
  __shared__ float s[TMAX];
  float q = qb[b * D + h * HD + lane];
  const float* Kb = sK + (((size_t)l * BB + b) * TMAX) * D + h * HD;
  for (int k = 0; k < T; k++) {
    float p = q * Kb[(size_t)k * D + lane];
    p = wredf(p);
    if (lane == 0) s[k] = p / 8.0f;   // / sqrt(64)
  }
  __syncthreads();
  float m = -INFINITY;
  for (int k = 0; k < T; k++) m = fmaxf(m, s[k]);
  float den = 0.f;
  for (int k = 0; k < T; k++) den += expf(s[k] - m);
  const float* Vb = sV + (((size_t)l * BB + b) * TMAX) * D + h * HD;
  float o = 0.f;
  for (int k = 0; k < T; k++) o += (expf(s[k] - m) / den) * Vb[(size_t)k * D + lane];
  ao[b * D + h * HD + lane] = o;
}

// ---------------- cross-attention over precomputed K/V (64 keys) ----------------
__global__ void attn_cross_k(const float* __restrict__ qb, const float* __restrict__ cK,
                             const float* __restrict__ cV, float* __restrict__ ao, int l)
{
  int b = blockIdx.x, h = blockIdx.y, lane = threadIdx.x;   // block 64
  __shared__ float s[KC];
  float q = qb[b * D + h * HD + lane];
  const float* Kb = cK + (((size_t)l * BB + b) * KC) * D + h * HD;
  for (int k = 0; k < KC; k++) {
    float p = q * Kb[(size_t)k * D + lane];
    p = wredf(p);
    if (lane == 0) s[k] = p / 8.0f;
  }
  __syncthreads();
  float m = -INFINITY;
  for (int k = 0; k < KC; k++) m = fmaxf(m, s[k]);
  float den = 0.f;
  for (int k = 0; k < KC; k++) den += expf(s[k] - m);
  const float* Vb = cV + (((size_t)l * BB + b) * KC) * D + h * HD;
  float o = 0.f;
  for (int k = 0; k < KC; k++) o += (expf(s[k] - m) / den) * Vb[(size_t)k * D + lane];
  ao[b * D + h * HD + lane] = o;
}

// ---------------- LayerNorm (reference op order) ----------------
__global__ void ln_k(const float* __restrict__ xin, const float* __restrict__ g,
                     const float* __restrict__ bb, float* __restrict__ xout)
{
  int b = blockIdx.x, tid = threadIdx.x;   // block 256
  __shared__ float red[256];
  __shared__ float smu, ssd;
  const float* xr = xin + b * D;
  float s = 0.f;
  for (int e = tid; e < D; e += 256) s += xr[e];
  red[tid] = s; __syncthreads();
  for (int o = 128; o > 0; o >>= 1) { if (tid < o) red[tid] += red[tid + o]; __syncthreads(); }
  if (tid == 0) smu = red[0] / (float)D;
  __syncthreads();
  float mu = smu, v = 0.f;
  for (int e = tid; e < D; e += 256) { float d0 = xr[e] - mu; v += d0 * d0; }
  red[tid] = v; __syncthreads();
  for (int o = 128; o > 0; o >>= 1) { if (tid < o) red[tid] += red[tid + o]; __syncthreads(); }
  if (tid == 0) ssd = sqrtf(red[0] / (float)D + 1e-5f);
  __syncthreads();
  float sd = ssd;
  for (int e = tid; e < D; e += 256) xout[b * D + e] = (xr[e] - mu) / sd * g[e] + bb[e];
}

// ---------------- tied-embedding logits: lg[b][v] = dot(x[b], emb[v]) ----------------
__global__ void logits_k(const float* __restrict__ x, const float* __restrict__ emb,
                         float* __restrict__ lg)
{
  __shared__ float xs[BB * D];  // 16 KB
  int tid = threadIdx.x;        // 256
  for (int e = tid; e < BB * D; e += 256) xs[e] = x[e];
  __syncthreads();
  int v = blockIdx.x * 4 + (tid >> 6);
  int lane = tid & 63;
  const float* er = emb + (size_t)v * D;
  float acc[BB];
#pragma unroll
  for (int b = 0; b < BB; b++) acc[b] = 0.f;
  for (int e = lane; e < D; e += 64) {
    float ev = er[e];
#pragma unroll
    for (int b = 0; b < BB; b++) acc[b] += ev * xs[b * D + e];
  }
#pragma unroll
  for (int b = 0; b < BB; b++) {
    float r = wredf(acc[b]);
    if (lane == 0) lg[(size_t)b * NV + v] = r;
  }
}

// ---------------- exact 50th-largest via 4-pass radix select ----------------
__global__ void topk_k(const float* __restrict__ lg, float* __restrict__ thr)
{
  int b = blockIdx.x, tid = threadIdx.x;   // block 256
  __shared__ unsigned hist[256];
  __shared__ unsigned sPrefix, sK_;
  if (tid == 0) { sPrefix = 0u; sK_ = KTOP; }
  for (int p = 0; p < 4; p++) {
    int shift = 24 - 8 * p;
    hist[tid] = 0u;
    __syncthreads();
    unsigned prefix = sPrefix;
    unsigned maskhi = (p == 0) ? 0u : (0xFFFFFFFFu << (shift + 8));
    for (int v = tid; v < NV; v += 256) {
      unsigned u = __float_as_uint(lg[(size_t)b * NV + v]);
      u = (u & 0x80000000u) ? ~u : (u | 0x80000000u);   // monotone key
      if (p == 0 || (u & maskhi) == prefix)
        atomicAdd(&hist[(u >> shift) & 0xFFu], 1u);
    }
    __syncthreads();
    if (tid == 0) {
      unsigned k = sK_, cum = 0;
      for (int bin = 255; bin >= 0; bin--) {
        cum += hist[bin];
        if (cum >= k) {
          sK_ = k - (cum - hist[bin]);
          sPrefix = prefix | ((unsigned)bin << shift);
          break;
        }
      }
    }
    __syncthreads();
  }
  if (tid == 0) {
    unsigned u = sPrefix;
    unsigned bits = (u & 0x80000000u) ? (u ^ 0x80000000u) : ~u;  // inverse transform
    thr[b] = __uint_as_float(bits);
  }
}

// ---------------- Gumbel-argmax sampling (jax partitionable threefry) ----------------
__global__ void sample_k(const float* __restrict__ lg, const float* __restrict__ thr,
                         int* __restrict__ fin, int* __restrict__ toks,
                         unsigned key0, unsigned key1, int t)
{
  int b = blockIdx.x, tid = threadIdx.x;   // block 256
  float th = thr[b];
  float best = -INFINITY; int bi = NV;
  for (int v = tid; v < NV; v += 256) {
    float lo = lg[(size_t)b * NV + v];
    float val = (lo < th) ? -INFINITY : lo;
    unsigned j = (unsigned)(b * NV + v);
    unsigned o0, o1;
    tf2x32(key0, key1, 0u, j, o0, o1);       // partitionable: counter = (hi=0, lo=j)
    unsigned bits = o0 ^ o1;                  // 32-bit combine
    unsigned ub = (bits >> 9) | 0x3f800000u;
    float f = __uint_as_float(ub) - 1.0f;
    const float TINY = 1.17549435e-38f;
    float u = f * (1.0f - TINY) + TINY;
    u = fmaxf(TINY, u);
    float g = -logf(-logf(u));
    float s = val + g;
    if (s > best || (s == best && v < bi)) { best = s; bi = v; }
  }
  __shared__ float bv[256]; __shared__ int bx[256];
  bv[tid] = best; bx[tid] = bi;
  __syncthreads();
  for (int o = 128; o > 0; o >>= 1) {
    if (tid < o) {
      if (bv[tid + o] > bv[tid] || (bv[tid + o] == bv[tid] && bx[tid + o] < bx[tid])) {
        bv[tid] = bv[tid + o]; bx[tid] = bx[tid + o];
      }
    }
    __syncthreads();
  }
  if (tid == 0) {
    int tok = bx[0];
    if (fin[b]) tok = PAD_ID;
    toks[b * TMAX + t + 1] = tok;
    if (tok == EOS_ID) fin[b] = 1;
  }
}

// ---------------- host orchestration ----------------
extern "C" void kernel_launch(void* const* d_in, const int* in_sizes, int n_in,
                              void* d_out, int out_size, void* d_ws, size_t ws_size,
                              hipStream_t stream)
{
  const float* state = (const float*)d_in[0];
  const float* emb   = (const float*)d_in[1];
  const float* qkv_w = (const float*)d_in[2];
  const float* qkv_b = (const float*)d_in[3];
  const float* out_w = (const float*)d_in[4];
  const float* out_b = (const float*)d_in[5];
  const float* f_w1  = (const float*)d_in[6];
  const float* f_b1  = (const float*)d_in[7];
  const float* f_w2  = (const float*)d_in[8];
  const float* f_b2  = (const float*)d_in[9];
  const float* lng   = (const float*)d_in[10];
  const float* lnb   = (const float*)d_in[11];

  float* ws = (float*)d_ws;
  float* cK = ws;
  float* cV = cK + (size_t)NL * BB * KC * D;
  float* sK = cV + (size_t)NL * BB * KC * D;
  float* sV = sK + (size_t)NL * BB * TMAX * D;
  float* x  = sV + (size_t)NL * BB * TMAX * D;
  float* xt = x  + BB * D;
  float* qb = xt + BB * D;
  float* ao = qb + BB * D;
  float* hb = ao + BB * D;
  float* lg = hb + BB * DFF;
  float* th = lg + (size_t)BB * NV;
  int*  fin = (int*)(th + BB);

  int* toks = (int*)d_out;

  // per-step fold_in keys: threefry2x32((0,1),(0,t)), computed on host
  unsigned sk0[STEPS], sk1[STEPS];
  for (int t = 0; t < STEPS; ++t) tf2x32(0u, 1u, 0u, (unsigned)t, sk0[t], sk1[t]);

  init_k<<<1, 64, 0, stream>>>(toks, fin);
  cross_kv_k<<<dim3(NL * KC * 256, BB), 256, 0, stream>>>(state, qkv_w, qkv_b, cK, cV);

  for (int t = 0; t < STEPS; ++t) {
    embed_k<<<BB, D, 0, stream>>>(toks, emb, x, t);
    for (int l = 0; l < NL; ++l) {
      const float* wqkv0 = qkv_w + ((size_t)l * 2 + 0) * (3 * D) * D;
      const float* bqkv0 = qkv_b + ((size_t)l * 2 + 0) * (3 * D);
      const float* wqkv1 = qkv_w + ((size_t)l * 2 + 1) * (3 * D) * D;  // rows 0..511 = q
      const float* bqkv1 = qkv_b + ((size_t)l * 2 + 1) * (3 * D);
      const float* wo0 = out_w + ((size_t)l * 2 + 0) * D * D;
      const float* bo0 = out_b + ((size_t)l * 2 + 0) * D;
      const float* wo1 = out_w + ((size_t)l * 2 + 1) * D * D;
      const float* bo1 = out_b + ((size_t)l * 2 + 1) * D;

      // self-attention block
      qkv_self_k<<<dim3(384, BB), 256, 0, stream>>>(x, wqkv0, bqkv0, qb, sK, sV, l, t);
      attn_self_k<<<dim3(BB, NH), 64, 0, stream>>>(qb, sK, sV, ao, l, t);
      gemv_k<0, 1><<<dim3(128, BB), 256, 0, stream>>>(ao, wo0, bo0, x, xt, D, D);
      ln_k<<<BB, 256, 0, stream>>>(xt, lng + ((size_t)l * 3 + 0) * D, lnb + ((size_t)l * 3 + 0) * D, x);

      // cross-attention block
      gemv_k<0, 0><<<dim3(128, BB), 256, 0, stream>>>(x, wqkv1, bqkv1, x, qb, D, D);
      attn_cross_k<<<dim3(BB, NH), 64, 0, stream>>>(qb, cK, cV, ao, l);
      gemv_k<0, 1><<<dim3(128, BB), 256, 0, stream>>>(ao, wo1, bo1, x, xt, D, D);
      ln_k<<<BB, 256, 0, stream>>>(xt, lng + ((size_t)l * 3 + 1) * D, lnb + ((size_t)l * 3 + 1) * D, x);

      // FFN block
      gemv_k<1, 0><<<dim3(512, BB), 256, 0, stream>>>(x, f_w1 + (size_t)l * DFF * D, f_b1 + (size_t)l * DFF, x, hb, D, DFF);
      gemv_k<0, 1><<<dim3(128, BB), 256, 0, stream>>>(hb, f_w2 + (size_t)l * D * DFF, f_b2 + (size_t)l * D, x, xt, DFF, D);
      ln_k<<<BB, 256, 0, stream>>>(xt, lng + ((size_t)l * 3 + 2) * D, lnb + ((size_t)l * 3 + 2) * D, x);
    }
    logits_k<<<NV / 4, 256, 0, stream>>>(x, emb, lg);
    topk_k<<<BB, 256, 0, stream>>>(lg, th);
    sample_k<<<BB, 256, 0, stream>>>(lg, th, fin, toks, sk0[t], sk1[t], t);
  }
}